// Round 2
// baseline (18761.806 us; speedup 1.0000x reference)
//
#include <hip/hip_runtime.h>

typedef short bf16x8 __attribute__((ext_vector_type(8)));
typedef float f32x4  __attribute__((ext_vector_type(4)));

#define MFMA16(a, b, c) __builtin_amdgcn_mfma_f32_16x16x32_bf16((a), (b), (c), 0, 0, 0)

// fp32 -> bf16 round-to-nearest-even
__device__ __forceinline__ unsigned short f2bf(float f) {
  union { float f; unsigned u; } v; v.f = f;
  unsigned u = v.u;
  u += 0x7fffu + ((u >> 16) & 1u);
  return (unsigned short)(u >> 16);
}
__device__ __forceinline__ float bf2f(unsigned short h) {
  union { unsigned u; float f; } v; v.u = ((unsigned)h) << 16;
  return v.f;
}
__device__ __forceinline__ float sigf(float x) { return 1.f / (1.f + __expf(-x)); }
__device__ __forceinline__ float tanh_(float x) {
  x = fminf(15.f, fmaxf(-15.f, x));
  float e = __expf(2.f * x);
  return (e - 1.f) / (e + 1.f);
}

// ---- manual grid barrier (device-scope, monotonic generation; no coop launch) ----
__device__ __forceinline__ void gbar(unsigned* cnt, unsigned* gen, unsigned nb,
                                     unsigned target) {
  __threadfence();                     // agent-scope release of h/zx stores
  __syncthreads();
  if (threadIdx.x == 0) {
    unsigned arr =
        __hip_atomic_fetch_add(cnt, 1u, __ATOMIC_ACQ_REL, __HIP_MEMORY_SCOPE_AGENT);
    if (arr == target * nb - 1u) {
      __hip_atomic_store(gen, target, __ATOMIC_RELEASE, __HIP_MEMORY_SCOPE_AGENT);
    } else {
      while (__hip_atomic_load(gen, __ATOMIC_ACQUIRE, __HIP_MEMORY_SCOPE_AGENT) <
             target) {
        __builtin_amdgcn_s_sleep(1);
      }
    }
  }
  __syncthreads();
  __threadfence();                     // agent-scope acquire before h/zx reads
}

// ---------------- weight conversion fp32 -> bf16 ----------------
__global__ void k_conv(const float* __restrict__ wih, const float* __restrict__ whh,
                       unsigned short* __restrict__ oih, unsigned short* __restrict__ ohh) {
  const size_t NIH = (size_t)4096 * 512, NHH = (size_t)4096 * 1024;
  size_t i0 = ((size_t)blockIdx.x * blockDim.x + threadIdx.x) * 4;
  size_t gs = (size_t)gridDim.x * blockDim.x * 4;
  for (size_t j = i0; j < NIH; j += gs) {
    float4 v = *(const float4*)(wih + j);
    uint2 pk;
    pk.x = (unsigned)f2bf(v.x) | ((unsigned)f2bf(v.y) << 16);
    pk.y = (unsigned)f2bf(v.z) | ((unsigned)f2bf(v.w) << 16);
    *(uint2*)(oih + j) = pk;
  }
  for (size_t j = i0; j < NHH; j += gs) {
    float4 v = *(const float4*)(whh + j);
    uint2 pk;
    pk.x = (unsigned)f2bf(v.x) | ((unsigned)f2bf(v.y) << 16);
    pk.y = (unsigned)f2bf(v.z) | ((unsigned)f2bf(v.w) << 16);
    *(uint2*)(ohh + j) = pk;
  }
}

// ---------------- lengths / selection index ----------------
__global__ void k_tsel(const int* __restrict__ x, int* __restrict__ tsel,
                       int* __restrict__ padsel) {
  int b = threadIdx.x >> 3, j = threadIdx.x & 7;   // 512 threads: 64 b x 8 j
  int c = 0;
  for (int t = j * 64; t < j * 64 + 64; ++t) c += (x[b * 512 + t] != 1) ? 1 : 0;
  c += __shfl_xor(c, 1);
  c += __shfl_xor(c, 2);
  c += __shfl_xor(c, 4);
  if (j == 0) {
    int ts = (c - 1) & 511;                        // len==0 wraps to T-1 (JAX -1 indexing)
    tsel[b] = ts;
    padsel[b] = (x[b * 512 + ts] == 1) ? 1 : 0;    // masked_fill at the selected position
  }
}

// ---------------- final logits: [64,1024] @ [8,1024]^T + b ----------------
__global__ void k_logits(const float* __restrict__ finalb, const float* __restrict__ Wout,
                         const float* __restrict__ bout, float* __restrict__ out) {
  int tid = threadIdx.x;
  for (int e = tid; e < 512; e += 256) {
    int b = e >> 3, o = e & 7;
    const float* f = finalb + (size_t)b * 1024;
    const float* w = Wout + (size_t)o * 1024;
    float s = 0.f;
    for (int k = 0; k < 1024; ++k) s += f[k] * w[k];
    out[e] = s + bout[o];
  }
}

// ---------------- main kernel (plain launch; manual grid barrier) ----------------
// grid = 128 wgs x 256 thr. wg owns 8 h-cols (32 z-rows: 4 gates x 8).
struct SmemT {
  unsigned short sW[32][1032];                       // W_hh slice, n = gate*8 + hc_l, padded
  union {
    struct { unsigned short A[128][72]; unsigned short Bt[256][72]; } g;  // zx GEMM tiles
    struct { float z[64][33]; } rec;                 // z redistribute (recurrence)
    struct { unsigned short zs[128][128]; } zst;     // zx store staging
  } u;
};

__global__ __launch_bounds__(256, 1) void k_main(
    const int* __restrict__ x, const float* __restrict__ Wemb,
    const float* __restrict__ bih, const float* __restrict__ bhh,
    const unsigned short* __restrict__ Wihb, const unsigned short* __restrict__ Whhb,
    unsigned short* __restrict__ hT, float* __restrict__ finalb,
    const int* __restrict__ tsel, const int* __restrict__ padsel,
    unsigned short* __restrict__ zxr, unsigned* __restrict__ bar, int chunkT) {
  __shared__ SmemT smem;
  const int wg = blockIdx.x, tid = threadIdx.x;
  const int wave = tid >> 6, lane = tid & 63;
  const int l15 = lane & 15, lg = lane >> 4;
  unsigned* bcnt = bar;        // arrivals (monotonic)
  unsigned* bgen = bar + 32;   // generation (128 B away)
  unsigned bt = 0;

  // persistent W_hh slice -> LDS (rows: gate*8 + hc_l, global row gate*1024 + wg*8 + hc_l)
  for (int e = tid; e < 32 * 128; e += 256) {
    int n = e >> 7;
    int kq = (e & 127) << 3;
    int grow = (n >> 3) * 1024 + wg * 8 + (n & 7);
    *(uint4*)&smem.sW[n][kq] = *(const uint4*)(Whhb + (size_t)grow * 1024 + kq);
  }

  const int q = tid & 3;            // h-col pair index within wg slice
  const int my_b = tid >> 2;        // batch row for gate update
  float biasv[4][2];
#pragma unroll
  for (int g = 0; g < 4; ++g)
#pragma unroll
    for (int c = 0; c < 2; ++c) {
      int col = g * 1024 + wg * 8 + 2 * q + c;
      biasv[g][c] = bih[col] + bhh[col];
    }
  const int my_tsel = tsel[my_b];
  const int my_pad = padsel[my_b];
  float cc0 = 0.f, cc1 = 0.f;

  // zero h double-buffer slot 0 (visibility via first gbar)
  for (int e = wg * 256 + tid; e < 64 * 1024; e += 128 * 256) hT[e] = 0;

  const f32x4 fz = {0.f, 0.f, 0.f, 0.f};
  const int nChunks = 512 / chunkT;
  const int pmN = chunkT >> 1;        // 128-row m-blocks per chunk
  const int npatch = pmN * 16;        // x (4096/256) n-blocks

  for (int ch = 0; ch < nChunks; ++ch) {
    const int t0 = ch * chunkT;

    // ---- phase 1: zx[tl][b][:] = gather(Wemb, x) @ Wih^T  (bf16 MFMA, fp32 accum) ----
    for (int p = wg; p < npatch; p += 128) {
      const int pm = p % pmN;
      const int pn = p / pmN;
      const int n0 = pn * 256;
      f32x4 acc[8][4];
#pragma unroll
      for (int mt = 0; mt < 8; ++mt)
#pragma unroll
        for (int nt = 0; nt < 4; ++nt) acc[mt][nt] = fz;

      for (int kc = 0; kc < 512; kc += 64) {
        __syncthreads();
        {  // stage A: gathered embedding rows, fp32 -> bf16  ([128 m][64 k])
          int r = tid >> 1, half = (tid & 1) << 5;
          int tl = pm * 2 + (r >> 6), b = r & 63;
          int erow = x[b * 512 + t0 + tl];
          const float* srcp = Wemb + (size_t)erow * 512 + kc + half;
#pragma unroll
          for (int j = 0; j < 32; j += 4) {
            float4 v = *(const float4*)(srcp + j);
            uint2 pk;
            pk.x = (unsigned)f2bf(v.x) | ((unsigned)f2bf(v.y) << 16);
            pk.y = (unsigned)f2bf(v.z) | ((unsigned)f2bf(v.w) << 16);
            *(uint2*)&smem.u.g.A[r][half + j] = pk;
          }
        }
        {  // stage B: W_ih rows [n0 .. n0+255], bf16  ([256 n][64 k])
          const unsigned short* srcp = Wihb + (size_t)(n0 + tid) * 512 + kc;
#pragma unroll
          for (int j = 0; j < 64; j += 8)
            *(uint4*)&smem.u.g.Bt[tid][j] = *(const uint4*)(srcp + j);
        }
        __syncthreads();
#pragma unroll
        for (int ks = 0; ks < 64; ks += 32) {
          bf16x8 af[8];
#pragma unroll
          for (int mt = 0; mt < 8; ++mt)
            af[mt] = *(const bf16x8*)&smem.u.g.A[mt * 16 + l15][ks + (lg << 3)];
#pragma unroll
          for (int nt = 0; nt < 4; ++nt) {
            bf16x8 bfr =
                *(const bf16x8*)&smem.u.g.Bt[(wave * 4 + nt) * 16 + l15][ks + (lg << 3)];
#pragma unroll
            for (int mt = 0; mt < 8; ++mt)
              acc[mt][nt] = MFMA16(af[mt], bfr, acc[mt][nt]);
          }
        }
      }
      // store acc -> zx ring through LDS (coalesced), two 128-col halves
#pragma unroll
      for (int h = 0; h < 2; ++h) {
        __syncthreads();
        if ((wave >> 1) == h) {
#pragma unroll
          for (int mt = 0; mt < 8; ++mt)
#pragma unroll
            for (int nt = 0; nt < 4; ++nt)
#pragma unroll
              for (int r = 0; r < 4; ++r)
                smem.u.zst.zs[mt * 16 + (lg << 2) + r][(wave & 1) * 64 + nt * 16 + l15] =
                    f2bf(acc[mt][nt][r]);
        }
        __syncthreads();
        int m = tid >> 1, qq = (tid & 1) << 6;
        int tl2 = pm * 2 + (m >> 6), bb = m & 63;
        unsigned short* dst = zxr + ((size_t)(tl2 * 64 + bb)) * 4096 + n0 + h * 128 + qq;
#pragma unroll
        for (int j = 0; j < 64; j += 8)
          *(uint4*)(dst + j) = *(const uint4*)&smem.u.zst.zs[m][qq + j];
      }
    }

    gbar(bcnt, bgen, 128, ++bt);

    // ---- phase 2: chunkT recurrent steps ----
    for (int tl = 0; tl < chunkT; ++tl) {
      const int t = t0 + tl;
      const unsigned short* hprev = hT + (size_t)(t & 1) * 65536;
      unsigned short* hnext = hT + (size_t)((t & 1) ^ 1) * 65536;

      // z_h = h_prev @ W_hh_slice^T : wave owns m-tile = wave (b rows wave*16..+15)
      f32x4 r0 = fz, r1 = fz;
      const unsigned short* ap = hprev + (size_t)(wave * 16 + l15) * 1024 + (lg << 3);
#pragma unroll
      for (int kb = 0; kb < 1024; kb += 256) {
        bf16x8 afA[4], afB[4];
#pragma unroll
        for (int g = 0; g < 4; ++g) {
          afA[g] = *(const bf16x8*)(ap + kb + g * 64);
          afB[g] = *(const bf16x8*)(ap + kb + g * 64 + 32);
        }
#pragma unroll
        for (int g = 0; g < 4; ++g) {
          int ks = kb + g * 64;
          bf16x8 b0a = *(const bf16x8*)&smem.sW[l15][ks + (lg << 3)];
          bf16x8 b1a = *(const bf16x8*)&smem.sW[16 + l15][ks + (lg << 3)];
          r0 = MFMA16(afA[g], b0a, r0);
          r1 = MFMA16(afA[g], b1a, r1);
          bf16x8 b0b = *(const bf16x8*)&smem.sW[l15][ks + 32 + (lg << 3)];
          bf16x8 b1b = *(const bf16x8*)&smem.sW[16 + l15][ks + 32 + (lg << 3)];
          r0 = MFMA16(afB[g], b0b, r0);
          r1 = MFMA16(afB[g], b1b, r1);
        }
      }
      __syncthreads();
#pragma unroll
      for (int r = 0; r < 4; ++r) {
        smem.u.rec.z[wave * 16 + (lg << 2) + r][l15] = r0[r];
        smem.u.rec.z[wave * 16 + (lg << 2) + r][16 + l15] = r1[r];
      }
      __syncthreads();

      // gate update: thread -> (b = my_b, h-cols wg*8 + 2q, +1); c stays fp32 in regs
      const unsigned short* zxrow = zxr + (size_t)(tl * 64 + my_b) * 4096 + wg * 8 + 2 * q;
      unsigned vi = *(const unsigned*)(zxrow);
      unsigned vf = *(const unsigned*)(zxrow + 1024);
      unsigned vg = *(const unsigned*)(zxrow + 2048);
      unsigned vo = *(const unsigned*)(zxrow + 3072);
      int hc = 2 * q;
      float zi0 = smem.u.rec.z[my_b][hc]          + biasv[0][0] + bf2f(vi & 0xffffu);
      float zi1 = smem.u.rec.z[my_b][hc + 1]      + biasv[0][1] + bf2f(vi >> 16);
      float zf0 = smem.u.rec.z[my_b][8 + hc]      + biasv[1][0] + bf2f(vf & 0xffffu);
      float zf1 = smem.u.rec.z[my_b][8 + hc + 1]  + biasv[1][1] + bf2f(vf >> 16);
      float zg0 = smem.u.rec.z[my_b][16 + hc]     + biasv[2][0] + bf2f(vg & 0xffffu);
      float zg1 = smem.u.rec.z[my_b][16 + hc + 1] + biasv[2][1] + bf2f(vg >> 16);
      float zo0 = smem.u.rec.z[my_b][24 + hc]     + biasv[3][0] + bf2f(vo & 0xffffu);
      float zo1 = smem.u.rec.z[my_b][24 + hc + 1] + biasv[3][1] + bf2f(vo >> 16);

      cc0 = sigf(zf0) * cc0 + sigf(zi0) * tanh_(zg0);
      cc1 = sigf(zf1) * cc1 + sigf(zi1) * tanh_(zg1);
      float h0 = sigf(zo0) * tanh_(cc0);
      float h1 = sigf(zo1) * tanh_(cc1);

      if (t == my_tsel) {
        finalb[(size_t)my_b * 1024 + wg * 8 + hc]     = my_pad ? 0.f : h0;
        finalb[(size_t)my_b * 1024 + wg * 8 + hc + 1] = my_pad ? 0.f : h1;
      }
      unsigned hp = (unsigned)f2bf(h0) | ((unsigned)f2bf(h1) << 16);
      *(unsigned*)(hnext + (size_t)my_b * 1024 + wg * 8 + hc) = hp;

      gbar(bcnt, bgen, 128, ++bt);
    }
  }
}

extern "C" void kernel_launch(void* const* d_in, const int* in_sizes, int n_in,
                              void* d_out, int out_size, void* d_ws, size_t ws_size,
                              hipStream_t stream) {
  (void)in_sizes; (void)n_in; (void)out_size;
  const int*   x    = (const int*)  d_in[0];
  const float* Wemb = (const float*)d_in[1];
  const float* Wih  = (const float*)d_in[2];
  const float* Whh  = (const float*)d_in[3];
  const float* bih  = (const float*)d_in[4];
  const float* bhh  = (const float*)d_in[5];
  const float* Wout = (const float*)d_in[6];
  const float* bout = (const float*)d_in[7];
  float* out = (float*)d_out;
  char* ws = (char*)d_ws;

  constexpr size_t OFF_WIH = 0;
  constexpr size_t OFF_WHH = OFF_WIH + (size_t)4096 * 512 * 2;   //  4 MB
  constexpr size_t OFF_HT  = OFF_WHH + (size_t)4096 * 1024 * 2;  // +8 MB
  constexpr size_t OFF_FIN = OFF_HT + (size_t)2 * 64 * 1024 * 2; // +256 KB
  constexpr size_t OFF_TS  = OFF_FIN + (size_t)64 * 1024 * 4;    // +256 KB
  constexpr size_t OFF_PS  = OFF_TS + 256;
  constexpr size_t OFF_BAR = OFF_PS + 256;
  constexpr size_t OFF_ZX  = OFF_BAR + 256;

  unsigned short* wihb = (unsigned short*)(ws + OFF_WIH);
  unsigned short* whhb = (unsigned short*)(ws + OFF_WHH);
  unsigned short* hT   = (unsigned short*)(ws + OFF_HT);
  float* finalb        = (float*)(ws + OFF_FIN);
  int* tsel            = (int*)(ws + OFF_TS);
  int* padsel          = (int*)(ws + OFF_PS);
  unsigned* bar        = (unsigned*)(ws + OFF_BAR);
  unsigned short* zxr  = (unsigned short*)(ws + OFF_ZX);

  // adaptive zx-ring chunk (bytes = chunkT * 64 * 4096 * 2)
  int chunkT = 16;
  while (chunkT > 2 && OFF_ZX + (size_t)chunkT * 64 * 4096 * 2 > ws_size) chunkT >>= 1;

  hipMemsetAsync(ws + OFF_BAR, 0, 256, stream);     // barrier state must start at 0
  k_conv<<<2048, 256, 0, stream>>>(Wih, Whh, wihb, whhb);
  k_tsel<<<1, 512, 0, stream>>>(x, tsel, padsel);
  k_main<<<128, 256, 0, stream>>>(x, Wemb, bih, bhh, wihb, whhb, hT, finalb,
                                  tsel, padsel, zxr, bar, chunkT);
  k_logits<<<1, 256, 0, stream>>>(finalb, Wout, bout, out);
}

// Round 3
// 6640.257 us; speedup vs baseline: 2.8255x; 2.8255x over previous
//
#include <hip/hip_runtime.h>

typedef short bf16x8 __attribute__((ext_vector_type(8)));
typedef float f32x4  __attribute__((ext_vector_type(4)));

#define MFMA16(a, b, c) __builtin_amdgcn_mfma_f32_16x16x32_bf16((a), (b), (c), 0, 0, 0)

// fp32 -> bf16 round-to-nearest-even
__device__ __forceinline__ unsigned short f2bf(float f) {
  union { float f; unsigned u; } v; v.f = f;
  unsigned u = v.u;
  u += 0x7fffu + ((u >> 16) & 1u);
  return (unsigned short)(u >> 16);
}
__device__ __forceinline__ float bf2f(unsigned short h) {
  union { unsigned u; float f; } v; v.u = ((unsigned)h) << 16;
  return v.f;
}
__device__ __forceinline__ float sigf(float x) { return 1.f / (1.f + __expf(-x)); }
__device__ __forceinline__ float tanh_(float x) {
  x = fminf(15.f, fmaxf(-15.f, x));
  float e = __expf(2.f * x);
  return (e - 1.f) / (e + 1.f);
}

// ---- manual grid barrier ----
// Arrival: RELEASE fetch_add (flushes this wg's stores once).
// Spin: RELAXED loads (no per-poll cache invalidate!), then ONE acquire load.
__device__ __forceinline__ void gbar(unsigned* cnt, unsigned* gen, unsigned nb,
                                     unsigned target) {
  __syncthreads();
  if (threadIdx.x == 0) {
    unsigned arr =
        __hip_atomic_fetch_add(cnt, 1u, __ATOMIC_RELEASE, __HIP_MEMORY_SCOPE_AGENT);
    if (arr == target * nb - 1u) {
      __hip_atomic_store(gen, target, __ATOMIC_RELEASE, __HIP_MEMORY_SCOPE_AGENT);
    } else {
      while (__hip_atomic_load(gen, __ATOMIC_RELAXED, __HIP_MEMORY_SCOPE_AGENT) <
             target) {
        __builtin_amdgcn_s_sleep(2);
      }
    }
    // single acquire: invalidate stale L1/L2 exactly once per barrier
    (void)__hip_atomic_load(gen, __ATOMIC_ACQUIRE, __HIP_MEMORY_SCOPE_AGENT);
  }
  __syncthreads();
}

// ---------------- weight conversion fp32 -> bf16 ----------------
__global__ void k_conv(const float* __restrict__ wih, const float* __restrict__ whh,
                       unsigned short* __restrict__ oih, unsigned short* __restrict__ ohh) {
  const size_t NIH = (size_t)4096 * 512, NHH = (size_t)4096 * 1024;
  size_t i0 = ((size_t)blockIdx.x * blockDim.x + threadIdx.x) * 4;
  size_t gs = (size_t)gridDim.x * blockDim.x * 4;
  for (size_t j = i0; j < NIH; j += gs) {
    float4 v = *(const float4*)(wih + j);
    uint2 pk;
    pk.x = (unsigned)f2bf(v.x) | ((unsigned)f2bf(v.y) << 16);
    pk.y = (unsigned)f2bf(v.z) | ((unsigned)f2bf(v.w) << 16);
    *(uint2*)(oih + j) = pk;
  }
  for (size_t j = i0; j < NHH; j += gs) {
    float4 v = *(const float4*)(whh + j);
    uint2 pk;
    pk.x = (unsigned)f2bf(v.x) | ((unsigned)f2bf(v.y) << 16);
    pk.y = (unsigned)f2bf(v.z) | ((unsigned)f2bf(v.w) << 16);
    *(uint2*)(ohh + j) = pk;
  }
}

// ---------------- lengths / selection index ----------------
__global__ void k_tsel(const int* __restrict__ x, int* __restrict__ tsel,
                       int* __restrict__ padsel) {
  int b = threadIdx.x >> 3, j = threadIdx.x & 7;   // 512 threads: 64 b x 8 j
  int c = 0;
  for (int t = j * 64; t < j * 64 + 64; ++t) c += (x[b * 512 + t] != 1) ? 1 : 0;
  c += __shfl_xor(c, 1);
  c += __shfl_xor(c, 2);
  c += __shfl_xor(c, 4);
  if (j == 0) {
    int ts = (c - 1) & 511;                        // len==0 wraps to T-1 (JAX -1 indexing)
    tsel[b] = ts;
    padsel[b] = (x[b * 512 + ts] == 1) ? 1 : 0;    // masked_fill at the selected position
  }
}

// ---------------- final logits: [64,1024] @ [8,1024]^T + b ----------------
__global__ void k_logits(const float* __restrict__ finalb, const float* __restrict__ Wout,
                         const float* __restrict__ bout, float* __restrict__ out) {
  int tid = threadIdx.x;
  for (int e = tid; e < 512; e += 256) {
    int b = e >> 3, o = e & 7;
    const float* f = finalb + (size_t)b * 1024;
    const float* w = Wout + (size_t)o * 1024;
    float s = 0.f;
    for (int k = 0; k < 1024; ++k) s += f[k] * w[k];
    out[e] = s + bout[o];
  }
}

// ---------------- main kernel (plain launch; manual grid barrier) ----------------
// grid = 128 wgs x 256 thr. wg owns 8 h-cols (32 z-rows: 4 gates x 8).
struct SmemT {
  unsigned short sW[32][1032];                       // W_hh slice, n = gate*8 + hc_l, padded
  union {
    struct { unsigned short A[128][72]; unsigned short Bt[256][72]; } g;  // zx GEMM tiles
    struct { float z[64][33]; } rec;                 // z redistribute (recurrence)
    struct { unsigned short zs[128][136]; } zst;     // zx store staging (odd 16B stride)
  } u;
};

__global__ __launch_bounds__(256, 1) void k_main(
    const int* __restrict__ x, const float* __restrict__ Wemb,
    const float* __restrict__ bih, const float* __restrict__ bhh,
    const unsigned short* __restrict__ Wihb, const unsigned short* __restrict__ Whhb,
    unsigned short* __restrict__ hT, float* __restrict__ finalb,
    const int* __restrict__ tsel, const int* __restrict__ padsel,
    unsigned short* __restrict__ zxr, unsigned* __restrict__ bar, int chunkT) {
  __shared__ SmemT smem;
  const int wg = blockIdx.x, tid = threadIdx.x;
  const int wave = tid >> 6, lane = tid & 63;
  const int l15 = lane & 15, lg = lane >> 4;
  unsigned* bcnt = bar;        // arrivals (monotonic)
  unsigned* bgen = bar + 64;   // generation (256 B away)
  unsigned bt = 0;

  // persistent W_hh slice -> LDS (rows: gate*8 + hc_l, global row gate*1024 + wg*8 + hc_l)
  for (int e = tid; e < 32 * 128; e += 256) {
    int n = e >> 7;
    int kq = (e & 127) << 3;
    int grow = (n >> 3) * 1024 + wg * 8 + (n & 7);
    *(uint4*)&smem.sW[n][kq] = *(const uint4*)(Whhb + (size_t)grow * 1024 + kq);
  }

  const int q = tid & 3;            // h-col pair index within wg slice
  const int my_b = tid >> 2;        // batch row for gate update
  float biasv[4][2];
#pragma unroll
  for (int g = 0; g < 4; ++g)
#pragma unroll
    for (int c = 0; c < 2; ++c) {
      int col = g * 1024 + wg * 8 + 2 * q + c;
      biasv[g][c] = bih[col] + bhh[col];
    }
  const int my_tsel = tsel[my_b];
  const int my_pad = padsel[my_b];
  float cc0 = 0.f, cc1 = 0.f;

  // zero h double-buffer slot 0 (visibility via first gbar)
  for (int e = wg * 256 + tid; e < 64 * 1024; e += 128 * 256) hT[e] = 0;

  const f32x4 fz = {0.f, 0.f, 0.f, 0.f};
  const int nChunks = 512 / chunkT;
  const int pmN = chunkT >> 1;        // 128-row m-blocks per chunk
  const int npatch = pmN * 16;        // x (4096/256) n-blocks

  for (int ch = 0; ch < nChunks; ++ch) {
    const int t0 = ch * chunkT;

    // ---- phase 1: zx[tl][b][:] = gather(Wemb, x) @ Wih^T  (bf16 MFMA, fp32 accum) ----
    for (int p = wg; p < npatch; p += 128) {
      const int pm = p % pmN;
      const int pn = p / pmN;
      const int n0 = pn * 256;
      f32x4 acc[8][4];
#pragma unroll
      for (int mt = 0; mt < 8; ++mt)
#pragma unroll
        for (int nt = 0; nt < 4; ++nt) acc[mt][nt] = fz;

      for (int kc = 0; kc < 512; kc += 64) {
        __syncthreads();
        {  // stage A: gathered embedding rows, fp32 -> bf16  ([128 m][64 k])
          int r = tid >> 1, half = (tid & 1) << 5;
          int tl = pm * 2 + (r >> 6), b = r & 63;
          int erow = x[b * 512 + t0 + tl];
          const float* srcp = Wemb + (size_t)erow * 512 + kc + half;
#pragma unroll
          for (int j = 0; j < 32; j += 4) {
            float4 v = *(const float4*)(srcp + j);
            uint2 pk;
            pk.x = (unsigned)f2bf(v.x) | ((unsigned)f2bf(v.y) << 16);
            pk.y = (unsigned)f2bf(v.z) | ((unsigned)f2bf(v.w) << 16);
            *(uint2*)&smem.u.g.A[r][half + j] = pk;
          }
        }
        {  // stage B: W_ih rows [n0 .. n0+255], bf16  ([256 n][64 k])
          const unsigned short* srcp = Wihb + (size_t)(n0 + tid) * 512 + kc;
#pragma unroll
          for (int j = 0; j < 64; j += 8)
            *(uint4*)&smem.u.g.Bt[tid][j] = *(const uint4*)(srcp + j);
        }
        __syncthreads();
#pragma unroll
        for (int ks = 0; ks < 64; ks += 32) {
          bf16x8 af[8];
#pragma unroll
          for (int mt = 0; mt < 8; ++mt)
            af[mt] = *(const bf16x8*)&smem.u.g.A[mt * 16 + l15][ks + (lg << 3)];
#pragma unroll
          for (int nt = 0; nt < 4; ++nt) {
            bf16x8 bfr =
                *(const bf16x8*)&smem.u.g.Bt[(wave * 4 + nt) * 16 + l15][ks + (lg << 3)];
#pragma unroll
            for (int mt = 0; mt < 8; ++mt)
              acc[mt][nt] = MFMA16(af[mt], bfr, acc[mt][nt]);
          }
        }
      }
      // store acc -> zx ring through LDS (coalesced), two 128-col halves
#pragma unroll
      for (int h = 0; h < 2; ++h) {
        __syncthreads();
        if ((wave >> 1) == h) {
#pragma unroll
          for (int mt = 0; mt < 8; ++mt)
#pragma unroll
            for (int nt = 0; nt < 4; ++nt)
#pragma unroll
              for (int r = 0; r < 4; ++r)
                smem.u.zst.zs[mt * 16 + (lg << 2) + r][(wave & 1) * 64 + nt * 16 + l15] =
                    f2bf(acc[mt][nt][r]);
        }
        __syncthreads();
        int m = tid >> 1, qq = (tid & 1) << 6;
        int tl2 = pm * 2 + (m >> 6), bb = m & 63;
        unsigned short* dst = zxr + ((size_t)(tl2 * 64 + bb)) * 4096 + n0 + h * 128 + qq;
#pragma unroll
        for (int j = 0; j < 64; j += 8)
          *(uint4*)(dst + j) = *(const uint4*)&smem.u.zst.zs[m][qq + j];
      }
    }

    gbar(bcnt, bgen, 128, ++bt);

    // ---- phase 2: chunkT recurrent steps ----
    for (int tl = 0; tl < chunkT; ++tl) {
      const int t = t0 + tl;
      const unsigned short* hprev = hT + (size_t)(t & 1) * 65536;
      unsigned short* hnext = hT + (size_t)((t & 1) ^ 1) * 65536;

      // prefetch gate inputs (independent of z_h) so LLC latency hides under MFMAs
      const unsigned short* zxrow = zxr + (size_t)(tl * 64 + my_b) * 4096 + wg * 8 + 2 * q;
      unsigned vi = *(const unsigned*)(zxrow);
      unsigned vf = *(const unsigned*)(zxrow + 1024);
      unsigned vg = *(const unsigned*)(zxrow + 2048);
      unsigned vo = *(const unsigned*)(zxrow + 3072);

      // z_h = h_prev @ W_hh_slice^T : wave owns m-tile = wave (b rows wave*16..+15)
      f32x4 r0 = fz, r1 = fz;
      const unsigned short* ap = hprev + (size_t)(wave * 16 + l15) * 1024 + (lg << 3);
#pragma unroll
      for (int kb = 0; kb < 1024; kb += 256) {
        bf16x8 afA[4], afB[4];
#pragma unroll
        for (int g = 0; g < 4; ++g) {
          afA[g] = *(const bf16x8*)(ap + kb + g * 64);
          afB[g] = *(const bf16x8*)(ap + kb + g * 64 + 32);
        }
#pragma unroll
        for (int g = 0; g < 4; ++g) {
          int ks = kb + g * 64;
          bf16x8 b0a = *(const bf16x8*)&smem.sW[l15][ks + (lg << 3)];
          bf16x8 b1a = *(const bf16x8*)&smem.sW[16 + l15][ks + (lg << 3)];
          r0 = MFMA16(afA[g], b0a, r0);
          r1 = MFMA16(afA[g], b1a, r1);
          bf16x8 b0b = *(const bf16x8*)&smem.sW[l15][ks + 32 + (lg << 3)];
          bf16x8 b1b = *(const bf16x8*)&smem.sW[16 + l15][ks + 32 + (lg << 3)];
          r0 = MFMA16(afB[g], b0b, r0);
          r1 = MFMA16(afB[g], b1b, r1);
        }
      }
      __syncthreads();
#pragma unroll
      for (int r = 0; r < 4; ++r) {
        smem.u.rec.z[wave * 16 + (lg << 2) + r][l15] = r0[r];
        smem.u.rec.z[wave * 16 + (lg << 2) + r][16 + l15] = r1[r];
      }
      __syncthreads();

      // gate update: thread -> (b = my_b, h-cols wg*8 + 2q, +1); c stays fp32 in regs
      int hc = 2 * q;
      float zi0 = smem.u.rec.z[my_b][hc]          + biasv[0][0] + bf2f(vi & 0xffffu);
      float zi1 = smem.u.rec.z[my_b][hc + 1]      + biasv[0][1] + bf2f(vi >> 16);
      float zf0 = smem.u.rec.z[my_b][8 + hc]      + biasv[1][0] + bf2f(vf & 0xffffu);
      float zf1 = smem.u.rec.z[my_b][8 + hc + 1]  + biasv[1][1] + bf2f(vf >> 16);
      float zg0 = smem.u.rec.z[my_b][16 + hc]     + biasv[2][0] + bf2f(vg & 0xffffu);
      float zg1 = smem.u.rec.z[my_b][16 + hc + 1] + biasv[2][1] + bf2f(vg >> 16);
      float zo0 = smem.u.rec.z[my_b][24 + hc]     + biasv[3][0] + bf2f(vo & 0xffffu);
      float zo1 = smem.u.rec.z[my_b][24 + hc + 1] + biasv[3][1] + bf2f(vo >> 16);

      cc0 = sigf(zf0) * cc0 + sigf(zi0) * tanh_(zg0);
      cc1 = sigf(zf1) * cc1 + sigf(zi1) * tanh_(zg1);
      float h0 = sigf(zo0) * tanh_(cc0);
      float h1 = sigf(zo1) * tanh_(cc1);

      if (t == my_tsel) {
        finalb[(size_t)my_b * 1024 + wg * 8 + hc]     = my_pad ? 0.f : h0;
        finalb[(size_t)my_b * 1024 + wg * 8 + hc + 1] = my_pad ? 0.f : h1;
      }
      unsigned hp = (unsigned)f2bf(h0) | ((unsigned)f2bf(h1) << 16);
      *(unsigned*)(hnext + (size_t)my_b * 1024 + wg * 8 + hc) = hp;

      gbar(bcnt, bgen, 128, ++bt);
    }
  }
}

extern "C" void kernel_launch(void* const* d_in, const int* in_sizes, int n_in,
                              void* d_out, int out_size, void* d_ws, size_t ws_size,
                              hipStream_t stream) {
  (void)in_sizes; (void)n_in; (void)out_size;
  const int*   x    = (const int*)  d_in[0];
  const float* Wemb = (const float*)d_in[1];
  const float* Wih  = (const float*)d_in[2];
  const float* Whh  = (const float*)d_in[3];
  const float* bih  = (const float*)d_in[4];
  const float* bhh  = (const float*)d_in[5];
  const float* Wout = (const float*)d_in[6];
  const float* bout = (const float*)d_in[7];
  float* out = (float*)d_out;
  char* ws = (char*)d_ws;

  constexpr size_t OFF_WIH = 0;
  constexpr size_t OFF_WHH = OFF_WIH + (size_t)4096 * 512 * 2;   //  4 MB
  constexpr size_t OFF_HT  = OFF_WHH + (size_t)4096 * 1024 * 2;  // +8 MB
  constexpr size_t OFF_FIN = OFF_HT + (size_t)2 * 64 * 1024 * 2; // +256 KB
  constexpr size_t OFF_TS  = OFF_FIN + (size_t)64 * 1024 * 4;    // +256 KB
  constexpr size_t OFF_PS  = OFF_TS + 256;
  constexpr size_t OFF_BAR = OFF_PS + 256;
  constexpr size_t OFF_ZX  = OFF_BAR + 512;

  unsigned short* wihb = (unsigned short*)(ws + OFF_WIH);
  unsigned short* whhb = (unsigned short*)(ws + OFF_WHH);
  unsigned short* hT   = (unsigned short*)(ws + OFF_HT);
  float* finalb        = (float*)(ws + OFF_FIN);
  int* tsel            = (int*)(ws + OFF_TS);
  int* padsel          = (int*)(ws + OFF_PS);
  unsigned* bar        = (unsigned*)(ws + OFF_BAR);
  unsigned short* zxr  = (unsigned short*)(ws + OFF_ZX);

  // adaptive zx-ring chunk (bytes = chunkT * 64 * 4096 * 2)
  int chunkT = 16;
  while (chunkT > 2 && OFF_ZX + (size_t)chunkT * 64 * 4096 * 2 > ws_size) chunkT >>= 1;

  hipMemsetAsync(ws + OFF_BAR, 0, 512, stream);     // barrier state must start at 0
  k_conv<<<2048, 256, 0, stream>>>(Wih, Whh, wihb, whhb);
  k_tsel<<<1, 512, 0, stream>>>(x, tsel, padsel);
  k_main<<<128, 256, 0, stream>>>(x, Wemb, bih, bhh, wihb, whhb, hT, finalb,
                                  tsel, padsel, zxr, bar, chunkT);
  k_logits<<<1, 256, 0, stream>>>(finalb, Wout, bout, out);
}

// Round 4
// 6185.175 us; speedup vs baseline: 3.0334x; 1.0736x over previous
//
#include <hip/hip_runtime.h>

typedef short bf16x8 __attribute__((ext_vector_type(8)));
typedef float f32x4  __attribute__((ext_vector_type(4)));

#define MFMA16(a, b, c) __builtin_amdgcn_mfma_f32_16x16x32_bf16((a), (b), (c), 0, 0, 0)
#define AT_LD(p, o)    __hip_atomic_load((p), (o), __HIP_MEMORY_SCOPE_AGENT)
#define AT_ST(p, v, o) __hip_atomic_store((p), (v), (o), __HIP_MEMORY_SCOPE_AGENT)
#define AT_ADD(p, v, o) __hip_atomic_fetch_add((p), (v), (o), __HIP_MEMORY_SCOPE_AGENT)

// fp32 -> bf16 round-to-nearest-even
__device__ __forceinline__ unsigned short f2bf(float f) {
  union { float f; unsigned u; } v; v.f = f;
  unsigned u = v.u;
  u += 0x7fffu + ((u >> 16) & 1u);
  return (unsigned short)(u >> 16);
}
__device__ __forceinline__ float bf2f(unsigned short h) {
  union { unsigned u; float f; } v; v.u = ((unsigned)h) << 16;
  return v.f;
}
__device__ __forceinline__ float sigf(float x) { return 1.f / (1.f + __expf(-x)); }
__device__ __forceinline__ float tanh_(float x) {
  x = fminf(15.f, fmaxf(-15.f, x));
  float e = __expf(2.f * x);
  return (e - 1.f) / (e + 1.f);
}

// coherent (agent/sc1) 16B h-load as 2x relaxed u64 atomics: bypasses stale L2
__device__ __forceinline__ bf16x8 ld_h8(const unsigned short* p) {
  union { unsigned long long q[2]; bf16x8 v; } u;
  u.q[0] = AT_LD((const unsigned long long*)p, __ATOMIC_RELAXED);
  u.q[1] = AT_LD((const unsigned long long*)(p + 4), __ATOMIC_RELAXED);
  return u.v;
}

// ---- fence-free tree barrier for the 128 recurrent wgs (h data is sc1-coherent) ----
// bar words (256B-spaced): [0,64,128,192]=sub-counters, [256]=root, [320]=gen
__device__ __forceinline__ void gbar_rec(unsigned* bar, int wg, unsigned target) {
  __syncthreads();                       // drains vmcnt: h stores complete before arrival
  if (threadIdx.x == 0) {
    asm volatile("" ::: "memory");
    unsigned arr = AT_ADD(bar + (wg & 3) * 64, 1u, __ATOMIC_RELAXED);
    if (arr == target * 32u - 1u) {
      unsigned rarr = AT_ADD(bar + 256, 1u, __ATOMIC_RELAXED);
      if (rarr == target * 4u - 1u) AT_ST(bar + 320, target, __ATOMIC_RELAXED);
    }
    while (AT_LD(bar + 320, __ATOMIC_RELAXED) < target) __builtin_amdgcn_s_sleep(2);
    asm volatile("" ::: "memory");
  }
  __syncthreads();
}

// ---- per-chunk release barrier for the 128 GEMM wgs (flushes their zx stores) ----
// bar words: [384]=cnt, [448]=gen
__device__ __forceinline__ void gbar_gemm(unsigned* bar, unsigned target) {
  __syncthreads();
  if (threadIdx.x == 0) {
    unsigned arr = AT_ADD(bar + 384, 1u, __ATOMIC_RELEASE);   // vmcnt drain + L2 writeback
    if (arr == target * 128u - 1u) AT_ST(bar + 448, target, __ATOMIC_RELEASE);
    while (AT_LD(bar + 448, __ATOMIC_RELAXED) < target) __builtin_amdgcn_s_sleep(4);
    asm volatile("" ::: "memory");
  }
  __syncthreads();
}

// ---------------- weight conversion fp32 -> bf16 ----------------
__global__ void k_conv(const float* __restrict__ wih, const float* __restrict__ whh,
                       unsigned short* __restrict__ oih, unsigned short* __restrict__ ohh) {
  const size_t NIH = (size_t)4096 * 512, NHH = (size_t)4096 * 1024;
  size_t i0 = ((size_t)blockIdx.x * blockDim.x + threadIdx.x) * 4;
  size_t gs = (size_t)gridDim.x * blockDim.x * 4;
  for (size_t j = i0; j < NIH; j += gs) {
    float4 v = *(const float4*)(wih + j);
    uint2 pk;
    pk.x = (unsigned)f2bf(v.x) | ((unsigned)f2bf(v.y) << 16);
    pk.y = (unsigned)f2bf(v.z) | ((unsigned)f2bf(v.w) << 16);
    *(uint2*)(oih + j) = pk;
  }
  for (size_t j = i0; j < NHH; j += gs) {
    float4 v = *(const float4*)(whh + j);
    uint2 pk;
    pk.x = (unsigned)f2bf(v.x) | ((unsigned)f2bf(v.y) << 16);
    pk.y = (unsigned)f2bf(v.z) | ((unsigned)f2bf(v.w) << 16);
    *(uint2*)(ohh + j) = pk;
  }
}

// ---------------- lengths / selection index ----------------
__global__ void k_tsel(const int* __restrict__ x, int* __restrict__ tsel,
                       int* __restrict__ padsel) {
  int b = threadIdx.x >> 3, j = threadIdx.x & 7;   // 512 threads: 64 b x 8 j
  int c = 0;
  for (int t = j * 64; t < j * 64 + 64; ++t) c += (x[b * 512 + t] != 1) ? 1 : 0;
  c += __shfl_xor(c, 1);
  c += __shfl_xor(c, 2);
  c += __shfl_xor(c, 4);
  if (j == 0) {
    int ts = (c - 1) & 511;                        // len==0 wraps to T-1 (JAX -1 indexing)
    tsel[b] = ts;
    padsel[b] = (x[b * 512 + ts] == 1) ? 1 : 0;    // masked_fill at the selected position
  }
}

// ---------------- final logits: [64,1024] @ [8,1024]^T + b ----------------
__global__ void k_logits(const float* __restrict__ finalb, const float* __restrict__ Wout,
                         const float* __restrict__ bout, float* __restrict__ out) {
  int tid = threadIdx.x;
  for (int e = tid; e < 512; e += 256) {
    int b = e >> 3, o = e & 7;
    const float* f = finalb + (size_t)b * 1024;
    const float* w = Wout + (size_t)o * 1024;
    float s = 0.f;
    for (int k = 0; k < 1024; ++k) s += f[k] * w[k];
    out[e] = s + bout[o];
  }
}

// ---------------- main kernel: 256 wgs = 128 recurrent + 128 GEMM ----------------
struct SmemT {
  unsigned short sW[32][1032];                       // W_hh slice (rec wgs only)
  union {
    struct { unsigned short A[128][72]; unsigned short Bt[256][72]; } g;  // zx GEMM tiles
    struct { float z[64][33]; } rec;                 // z redistribute (recurrence)
    struct { unsigned short zs[128][136]; } zst;     // zx store staging
  } u;
};

__global__ __launch_bounds__(256, 1) void k_main(
    const int* __restrict__ x, const float* __restrict__ Wemb,
    const float* __restrict__ bih, const float* __restrict__ bhh,
    const unsigned short* __restrict__ Wihb, const unsigned short* __restrict__ Whhb,
    unsigned short* __restrict__ hT, float* __restrict__ finalb,
    const int* __restrict__ tsel, const int* __restrict__ padsel,
    unsigned short* __restrict__ zxr, unsigned* __restrict__ bar, int chunkT) {
  __shared__ SmemT smem;
  const int wg = blockIdx.x, tid = threadIdx.x;
  const int wave = tid >> 6, lane = tid & 63;
  const int l15 = lane & 15, lg = lane >> 4;
  unsigned* gemm_done = bar + 512;
  unsigned* rec_done  = bar + 576;

  const f32x4 fz = {0.f, 0.f, 0.f, 0.f};
  const int nChunks = 512 / chunkT;
  const size_t slotE = (size_t)chunkT * 64 * 4096;   // zx slot elements

  if (wg < 128) {
    // ================= RECURRENT ROLE =================
    // persistent W_hh slice -> LDS (rows: gate*8 + hc_l)
    for (int e = tid; e < 32 * 128; e += 256) {
      int n = e >> 7;
      int kq = (e & 127) << 3;
      int grow = (n >> 3) * 1024 + wg * 8 + (n & 7);
      *(uint4*)&smem.sW[n][kq] = *(const uint4*)(Whhb + (size_t)grow * 1024 + kq);
    }
    const int q = tid & 3;
    const int my_b = tid >> 2;
    const int zc = wg * 8 + 2 * q;                   // my z/h column (pair base)
    float biasv[4][2];
#pragma unroll
    for (int g = 0; g < 4; ++g)
#pragma unroll
      for (int c = 0; c < 2; ++c) biasv[g][c] = bih[g * 1024 + zc + c] + bhh[g * 1024 + zc + c];
    const int my_tsel = tsel[my_b];
    const int my_pad = padsel[my_b];
    float cc0 = 0.f, cc1 = 0.f;
    unsigned bt = 0;

    // zero h slot 0 with coherent stores (one u32 per thread: 128*256 == 32768)
    AT_ST((unsigned*)hT + (wg * 256 + tid), 0u, __ATOMIC_RELAXED);
    gbar_rec(bar, wg, ++bt);

    for (int ch = 0; ch < nChunks; ++ch) {
      const int t0 = ch * chunkT;
      const unsigned short* zxbase = zxr + (size_t)(ch & 1) * slotE;

      // wait for GEMM wgs to publish this chunk's zx; ONE acquire-inv per chunk
      if (tid == 0) {
        while (AT_LD(gemm_done, __ATOMIC_RELAXED) < (unsigned)(ch + 1))
          __builtin_amdgcn_s_sleep(4);
        (void)AT_LD(gemm_done, __ATOMIC_ACQUIRE);    // buffer_inv: see fresh zx
        asm volatile("" ::: "memory");
      }
      __syncthreads();

      // prefetch zx for tl=0
      const unsigned short* zr0 = zxbase + (size_t)my_b * 4096 + zc;
      unsigned vi = *(const unsigned*)(zr0);
      unsigned vf = *(const unsigned*)(zr0 + 1024);
      unsigned vg = *(const unsigned*)(zr0 + 2048);
      unsigned vo = *(const unsigned*)(zr0 + 3072);

      for (int tl = 0; tl < chunkT; ++tl) {
        const int t = t0 + tl;
        const unsigned short* hprev = hT + (size_t)(t & 1) * 65536;
        unsigned short* hnext = hT + (size_t)((t & 1) ^ 1) * 65536;

        // z_h = h_prev @ W_hh_slice^T (h via coherent sc1 loads)
        f32x4 r0 = fz, r1 = fz;
        const unsigned short* ap = hprev + (size_t)(wave * 16 + l15) * 1024 + (lg << 3);
#pragma unroll
        for (int kb = 0; kb < 1024; kb += 256) {
          bf16x8 afA[4], afB[4];
#pragma unroll
          for (int g = 0; g < 4; ++g) {
            afA[g] = ld_h8(ap + kb + g * 64);
            afB[g] = ld_h8(ap + kb + g * 64 + 32);
          }
#pragma unroll
          for (int g = 0; g < 4; ++g) {
            int ks = kb + g * 64;
            bf16x8 b0a = *(const bf16x8*)&smem.sW[l15][ks + (lg << 3)];
            bf16x8 b1a = *(const bf16x8*)&smem.sW[16 + l15][ks + (lg << 3)];
            r0 = MFMA16(afA[g], b0a, r0);
            r1 = MFMA16(afA[g], b1a, r1);
            bf16x8 b0b = *(const bf16x8*)&smem.sW[l15][ks + 32 + (lg << 3)];
            bf16x8 b1b = *(const bf16x8*)&smem.sW[16 + l15][ks + 32 + (lg << 3)];
            r0 = MFMA16(afB[g], b0b, r0);
            r1 = MFMA16(afB[g], b1b, r1);
          }
        }
        __syncthreads();
#pragma unroll
        for (int r = 0; r < 4; ++r) {
          smem.u.rec.z[wave * 16 + (lg << 2) + r][l15] = r0[r];
          smem.u.rec.z[wave * 16 + (lg << 2) + r][16 + l15] = r1[r];
        }
        __syncthreads();

        int hc = 2 * q;
        float zi0 = smem.u.rec.z[my_b][hc]          + biasv[0][0] + bf2f(vi & 0xffffu);
        float zi1 = smem.u.rec.z[my_b][hc + 1]      + biasv[0][1] + bf2f(vi >> 16);
        float zf0 = smem.u.rec.z[my_b][8 + hc]      + biasv[1][0] + bf2f(vf & 0xffffu);
        float zf1 = smem.u.rec.z[my_b][8 + hc + 1]  + biasv[1][1] + bf2f(vf >> 16);
        float zg0 = smem.u.rec.z[my_b][16 + hc]     + biasv[2][0] + bf2f(vg & 0xffffu);
        float zg1 = smem.u.rec.z[my_b][16 + hc + 1] + biasv[2][1] + bf2f(vg >> 16);
        float zo0 = smem.u.rec.z[my_b][24 + hc]     + biasv[3][0] + bf2f(vo & 0xffffu);
        float zo1 = smem.u.rec.z[my_b][24 + hc + 1] + biasv[3][1] + bf2f(vo >> 16);

        cc0 = sigf(zf0) * cc0 + sigf(zi0) * tanh_(zg0);
        cc1 = sigf(zf1) * cc1 + sigf(zi1) * tanh_(zg1);
        float h0 = sigf(zo0) * tanh_(cc0);
        float h1 = sigf(zo1) * tanh_(cc1);

        if (t == my_tsel) {
          finalb[(size_t)my_b * 1024 + zc]     = my_pad ? 0.f : h0;
          finalb[(size_t)my_b * 1024 + zc + 1] = my_pad ? 0.f : h1;
        }
        unsigned hp = (unsigned)f2bf(h0) | ((unsigned)f2bf(h1) << 16);
        AT_ST((unsigned*)(hnext + (size_t)my_b * 1024 + zc), hp, __ATOMIC_RELAXED);

        // prefetch next step's zx before the barrier (slot data is stable in-chunk)
        if (tl + 1 < chunkT) {
          const unsigned short* zn = zxbase + (size_t)((tl + 1) * 64 + my_b) * 4096 + zc;
          vi = *(const unsigned*)(zn);
          vf = *(const unsigned*)(zn + 1024);
          vg = *(const unsigned*)(zn + 2048);
          vo = *(const unsigned*)(zn + 3072);
        }
        gbar_rec(bar, wg, ++bt);
      }
      if (wg == 0 && tid == 0) AT_ST(rec_done, (unsigned)(ch + 1), __ATOMIC_RELAXED);
    }
  } else {
    // ================= GEMM ROLE (zx producer, one chunk ahead) =================
    const int gw = wg - 128;
    unsigned gt = 0;
    for (int ch = 0; ch < nChunks; ++ch) {
      // slot ch&1 was last consumed in chunk ch-2; wait until rec finished it
      if (tid == 0 && ch >= 2) {
        while (AT_LD(rec_done, __ATOMIC_RELAXED) < (unsigned)(ch - 1))
          __builtin_amdgcn_s_sleep(4);
        asm volatile("" ::: "memory");
      }
      __syncthreads();

      const int t0 = ch * chunkT;
      unsigned short* zx = zxr + (size_t)(ch & 1) * slotE;
      const int pmN = chunkT >> 1;
      const int npatch = pmN * 16;

      for (int p = gw; p < npatch; p += 128) {
        const int pm = p % pmN;
        const int n0 = (p / pmN) * 256;
        f32x4 acc[8][4];
#pragma unroll
        for (int mt = 0; mt < 8; ++mt)
#pragma unroll
          for (int nt = 0; nt < 4; ++nt) acc[mt][nt] = fz;

        for (int kc = 0; kc < 512; kc += 64) {
          __syncthreads();
          {  // stage A: gathered embedding rows, fp32 -> bf16  ([128 m][64 k])
            int r = tid >> 1, half = (tid & 1) << 5;
            int tl = pm * 2 + (r >> 6), b = r & 63;
            int erow = x[b * 512 + t0 + tl];
            const float* srcp = Wemb + (size_t)erow * 512 + kc + half;
#pragma unroll
            for (int j = 0; j < 32; j += 4) {
              float4 v = *(const float4*)(srcp + j);
              uint2 pk;
              pk.x = (unsigned)f2bf(v.x) | ((unsigned)f2bf(v.y) << 16);
              pk.y = (unsigned)f2bf(v.z) | ((unsigned)f2bf(v.w) << 16);
              *(uint2*)&smem.u.g.A[r][half + j] = pk;
            }
          }
          {  // stage B: W_ih rows [n0 .. n0+255]  ([256 n][64 k])
            const unsigned short* srcp = Wihb + (size_t)(n0 + tid) * 512 + kc;
#pragma unroll
            for (int j = 0; j < 64; j += 8)
              *(uint4*)&smem.u.g.Bt[tid][j] = *(const uint4*)(srcp + j);
          }
          __syncthreads();
#pragma unroll
          for (int ks = 0; ks < 64; ks += 32) {
            bf16x8 af[8];
#pragma unroll
            for (int mt = 0; mt < 8; ++mt)
              af[mt] = *(const bf16x8*)&smem.u.g.A[mt * 16 + l15][ks + (lg << 3)];
#pragma unroll
            for (int nt = 0; nt < 4; ++nt) {
              bf16x8 bfr =
                  *(const bf16x8*)&smem.u.g.Bt[(wave * 4 + nt) * 16 + l15][ks + (lg << 3)];
#pragma unroll
              for (int mt = 0; mt < 8; ++mt)
                acc[mt][nt] = MFMA16(af[mt], bfr, acc[mt][nt]);
            }
          }
        }
        // store acc -> zx slot through LDS (coalesced), two 128-col halves
#pragma unroll
        for (int h = 0; h < 2; ++h) {
          __syncthreads();
          if ((wave >> 1) == h) {
#pragma unroll
            for (int mt = 0; mt < 8; ++mt)
#pragma unroll
              for (int nt = 0; nt < 4; ++nt)
#pragma unroll
                for (int r = 0; r < 4; ++r)
                  smem.u.zst.zs[mt * 16 + (lg << 2) + r][(wave & 1) * 64 + nt * 16 + l15] =
                      f2bf(acc[mt][nt][r]);
          }
          __syncthreads();
          int m = tid >> 1, qq = (tid & 1) << 6;
          int tl2 = pm * 2 + (m >> 6), bb = m & 63;
          unsigned short* dst = zx + ((size_t)(tl2 * 64 + bb)) * 4096 + n0 + h * 128 + qq;
#pragma unroll
          for (int j = 0; j < 64; j += 8)
            *(uint4*)(dst + j) = *(const uint4*)&smem.u.zst.zs[m][qq + j];
        }
      }
      gbar_gemm(bar, ++gt);                          // release: flush zx to LLC
      if (wg == 128 && tid == 0) AT_ST(gemm_done, gt, __ATOMIC_RELAXED);
    }
  }
}

extern "C" void kernel_launch(void* const* d_in, const int* in_sizes, int n_in,
                              void* d_out, int out_size, void* d_ws, size_t ws_size,
                              hipStream_t stream) {
  (void)in_sizes; (void)n_in; (void)out_size;
  const int*   x    = (const int*)  d_in[0];
  const float* Wemb = (const float*)d_in[1];
  const float* Wih  = (const float*)d_in[2];
  const float* Whh  = (const float*)d_in[3];
  const float* bih  = (const float*)d_in[4];
  const float* bhh  = (const float*)d_in[5];
  const float* Wout = (const float*)d_in[6];
  const float* bout = (const float*)d_in[7];
  float* out = (float*)d_out;
  char* ws = (char*)d_ws;

  constexpr size_t OFF_WIH = 0;
  constexpr size_t OFF_WHH = OFF_WIH + (size_t)4096 * 512 * 2;   //  4 MB
  constexpr size_t OFF_HT  = OFF_WHH + (size_t)4096 * 1024 * 2;  // +8 MB
  constexpr size_t OFF_FIN = OFF_HT + (size_t)2 * 64 * 1024 * 2; // +256 KB
  constexpr size_t OFF_TS  = OFF_FIN + (size_t)64 * 1024 * 4;    // +256 KB
  constexpr size_t OFF_PS  = OFF_TS + 256;
  constexpr size_t OFF_BAR = OFF_PS + 256;
  constexpr size_t OFF_ZX  = OFF_BAR + 4096;

  unsigned short* wihb = (unsigned short*)(ws + OFF_WIH);
  unsigned short* whhb = (unsigned short*)(ws + OFF_WHH);
  unsigned short* hT   = (unsigned short*)(ws + OFF_HT);
  float* finalb        = (float*)(ws + OFF_FIN);
  int* tsel            = (int*)(ws + OFF_TS);
  int* padsel          = (int*)(ws + OFF_PS);
  unsigned* bar        = (unsigned*)(ws + OFF_BAR);
  unsigned short* zxr  = (unsigned short*)(ws + OFF_ZX);

  // adaptive zx ring: 2 slots x chunkT*64*4096*2 bytes
  int chunkT = 16;
  while (chunkT > 2 &&
         OFF_ZX + (size_t)2 * chunkT * 64 * 4096 * 2 > ws_size)
    chunkT >>= 1;

  hipMemsetAsync(ws + OFF_BAR, 0, 4096, stream);    // barrier/handshake state = 0
  k_conv<<<2048, 256, 0, stream>>>(Wih, Whh, wihb, whhb);
  k_tsel<<<1, 512, 0, stream>>>(x, tsel, padsel);
  k_main<<<256, 256, 0, stream>>>(x, Wemb, bih, bhh, wihb, whhb, hT, finalb,
                                  tsel, padsel, zxr, bar, chunkT);
  k_logits<<<1, 256, 0, stream>>>(finalb, Wout, bout, out);
}

// Round 5
// 3602.109 us; speedup vs baseline: 5.2086x; 1.7171x over previous
//
#include <hip/hip_runtime.h>

typedef short bf16x8 __attribute__((ext_vector_type(8)));
typedef float f32x4  __attribute__((ext_vector_type(4)));

#define MFMA16(a, b, c) __builtin_amdgcn_mfma_f32_16x16x32_bf16((a), (b), (c), 0, 0, 0)
#define AT_LD(p, o)    __hip_atomic_load((p), (o), __HIP_MEMORY_SCOPE_AGENT)
#define AT_ST(p, v, o) __hip_atomic_store((p), (v), (o), __HIP_MEMORY_SCOPE_AGENT)
#define AT_ADD(p, v, o) __hip_atomic_fetch_add((p), (v), (o), __HIP_MEMORY_SCOPE_AGENT)

#define HSLOT 67584      // h ring slot stride in bf16 elems (128KB + 4KB pad)

// fp32 -> bf16 round-to-nearest-even
__device__ __forceinline__ unsigned short f2bf(float f) {
  union { float f; unsigned u; } v; v.f = f;
  unsigned u = v.u;
  u += 0x7fffu + ((u >> 16) & 1u);
  return (unsigned short)(u >> 16);
}
__device__ __forceinline__ float bf2f(unsigned short h) {
  union { unsigned u; float f; } v; v.u = ((unsigned)h) << 16;
  return v.f;
}
__device__ __forceinline__ float sigf(float x) { return 1.f / (1.f + __expf(-x)); }
__device__ __forceinline__ float tanh_(float x) {
  x = fminf(15.f, fmaxf(-15.f, x));
  float e = __expf(2.f * x);
  return (e - 1.f) / (e + 1.f);
}

// ---- relaxed tree barrier for the 128 recurrent wgs (h data goes sc1->LLC) ----
// bar words (256B-spaced): [0,64,128,192]=sub-counters, [256]=root, [320]=gen
__device__ __forceinline__ void gbar_rec(unsigned* bar, int wg, unsigned target) {
  __syncthreads();                 // drains vmcnt: h sc1 stores complete before arrival
  if (threadIdx.x == 0) {
    asm volatile("" ::: "memory");
    unsigned arr = AT_ADD(bar + (wg & 3) * 64, 1u, __ATOMIC_RELAXED);
    if (arr == target * 32u - 1u) {
      unsigned rarr = AT_ADD(bar + 256, 1u, __ATOMIC_RELAXED);
      if (rarr == target * 4u - 1u) AT_ST(bar + 320, target, __ATOMIC_RELAXED);
    }
    while (AT_LD(bar + 320, __ATOMIC_RELAXED) < target) __builtin_amdgcn_s_sleep(2);
    asm volatile("" ::: "memory");
  }
  __syncthreads();
}

// ---- per-chunk release barrier for the 128 GEMM wgs (flushes their zx stores) ----
// bar words: [384]=cnt, [448]=gen
__device__ __forceinline__ void gbar_gemm(unsigned* bar, unsigned target) {
  __syncthreads();
  if (threadIdx.x == 0) {
    unsigned arr = AT_ADD(bar + 384, 1u, __ATOMIC_RELEASE);   // vmcnt drain + L2 writeback
    if (arr == target * 128u - 1u) AT_ST(bar + 448, target, __ATOMIC_RELEASE);
    while (AT_LD(bar + 448, __ATOMIC_RELAXED) < target) __builtin_amdgcn_s_sleep(4);
    asm volatile("" ::: "memory");
  }
  __syncthreads();
}

// ---------------- weight conversion fp32 -> bf16 ----------------
__global__ void k_conv(const float* __restrict__ wih, const float* __restrict__ whh,
                       const float* __restrict__ wemb,
                       unsigned short* __restrict__ oih, unsigned short* __restrict__ ohh,
                       unsigned short* __restrict__ oemb) {
  const size_t NIH = (size_t)4096 * 512, NHH = (size_t)4096 * 1024;
  const size_t NE = (size_t)32000 * 512;
  size_t i0 = ((size_t)blockIdx.x * blockDim.x + threadIdx.x) * 4;
  size_t gs = (size_t)gridDim.x * blockDim.x * 4;
  for (size_t j = i0; j < NIH; j += gs) {
    float4 v = *(const float4*)(wih + j);
    uint2 pk;
    pk.x = (unsigned)f2bf(v.x) | ((unsigned)f2bf(v.y) << 16);
    pk.y = (unsigned)f2bf(v.z) | ((unsigned)f2bf(v.w) << 16);
    *(uint2*)(oih + j) = pk;
  }
  for (size_t j = i0; j < NHH; j += gs) {
    float4 v = *(const float4*)(whh + j);
    uint2 pk;
    pk.x = (unsigned)f2bf(v.x) | ((unsigned)f2bf(v.y) << 16);
    pk.y = (unsigned)f2bf(v.z) | ((unsigned)f2bf(v.w) << 16);
    *(uint2*)(ohh + j) = pk;
  }
  if (oemb)
    for (size_t j = i0; j < NE; j += gs) {
      float4 v = *(const float4*)(wemb + j);
      uint2 pk;
      pk.x = (unsigned)f2bf(v.x) | ((unsigned)f2bf(v.y) << 16);
      pk.y = (unsigned)f2bf(v.z) | ((unsigned)f2bf(v.w) << 16);
      *(uint2*)(oemb + j) = pk;
    }
}

// ---------------- lengths / selection index ----------------
__global__ void k_tsel(const int* __restrict__ x, int* __restrict__ tsel,
                       int* __restrict__ padsel) {
  int b = threadIdx.x >> 3, j = threadIdx.x & 7;   // 512 threads: 64 b x 8 j
  int c = 0;
  for (int t = j * 64; t < j * 64 + 64; ++t) c += (x[b * 512 + t] != 1) ? 1 : 0;
  c += __shfl_xor(c, 1);
  c += __shfl_xor(c, 2);
  c += __shfl_xor(c, 4);
  if (j == 0) {
    int ts = (c - 1) & 511;                        // len==0 wraps to T-1 (JAX -1 indexing)
    tsel[b] = ts;
    padsel[b] = (x[b * 512 + ts] == 1) ? 1 : 0;    // masked_fill at the selected position
  }
}

// ---------------- final logits: [64,1024] @ [8,1024]^T + b ----------------
__global__ void k_logits(const float* __restrict__ finalb, const float* __restrict__ Wout,
                         const float* __restrict__ bout, float* __restrict__ out) {
  int tid = threadIdx.x;
  for (int e = tid; e < 512; e += 256) {
    int b = e >> 3, o = e & 7;
    const float* f = finalb + (size_t)b * 1024;
    const float* w = Wout + (size_t)o * 1024;
    float s = 0.f;
    for (int k = 0; k < 1024; ++k) s += f[k] * w[k];
    out[e] = s + bout[o];
  }
}

// ---------------- main kernel: 256 wgs = 128 recurrent + 128 GEMM ----------------
struct SmemT {
  unsigned short sW[32][1032];                       // W_hh slice (rec wgs only)
  union {
    struct { unsigned short A[128][72]; unsigned short Bt[256][72]; } g;  // zx GEMM tiles
    struct { float z[64][33]; } rec;                 // z redistribute (recurrence)
    struct { unsigned short zs[128][136]; } zst;     // zx store staging
  } u;
};

__global__ __launch_bounds__(256, 1) void k_main(
    const int* __restrict__ x, const float* __restrict__ Wemb,
    const float* __restrict__ bih, const float* __restrict__ bhh,
    const unsigned short* __restrict__ Wihb, const unsigned short* __restrict__ Whhb,
    const unsigned short* __restrict__ wembb,          // bf16 Wemb (may be null)
    unsigned short* __restrict__ hr,                   // h fragment ring, 16 slots
    float* __restrict__ finalb,
    const int* __restrict__ tsel, const int* __restrict__ padsel,
    unsigned short* __restrict__ zxr, unsigned* __restrict__ bar, int chunkT) {
  __shared__ SmemT smem;
  const int wg = blockIdx.x, tid = threadIdx.x;
  const int wave = tid >> 6, lane = tid & 63;
  const int l15 = lane & 15, lg = lane >> 4;
  unsigned* gemm_done = bar + 512;
  unsigned* rec_done  = bar + 576;

  const f32x4 fz = {0.f, 0.f, 0.f, 0.f};
  const int nChunks = 512 / chunkT;
  const size_t slotE = (size_t)chunkT * 64 * 4096;   // zx slot elements

  if (wg < 128) {
    // ================= RECURRENT ROLE =================
    // persistent W_hh slice -> LDS (rows: gate*8 + hc_l)
    for (int e = tid; e < 32 * 128; e += 256) {
      int n = e >> 7;
      int kq = (e & 127) << 3;
      int grow = (n >> 3) * 1024 + wg * 8 + (n & 7);
      *(uint4*)&smem.sW[n][kq] = *(const uint4*)(Whhb + (size_t)grow * 1024 + kq);
    }
    const int q = tid & 3;
    const int my_b = tid >> 2;
    const int zc = wg * 8 + 2 * q;                   // my z/h column (pair base)
    float biasv[4][2];
#pragma unroll
    for (int g = 0; g < 4; ++g)
#pragma unroll
      for (int c = 0; c < 2; ++c) biasv[g][c] = bih[g * 1024 + zc + c] + bhh[g * 1024 + zc + c];
    const int my_tsel = tsel[my_b];
    const int my_pad = padsel[my_b];
    // h fragment-order store offset for this thread's (b, col pair)
    const size_t hwe = (size_t)((my_b >> 4) * 32 + (wg >> 2)) * 512 +
                       (size_t)(wg & 3) * 128 + (size_t)(my_b & 15) * 8 + 2 * q;
    float cc0 = 0.f, cc1 = 0.f;
    unsigned bt = 0;

    // zero h slot 0 with sc1 stores (128 wg x 256 thr == 32768 u32 == 128KB)
    AT_ST((unsigned*)hr + (wg * 256 + tid), 0u, __ATOMIC_RELAXED);
    gbar_rec(bar, wg, ++bt);

    for (int ch = 0; ch < nChunks; ++ch) {
      const int t0 = ch * chunkT;
      const unsigned short* zxbase = zxr + (size_t)(ch & 1) * slotE;

      // wait for GEMM wgs to publish this chunk's zx; ONE acquire-inv per chunk.
      // (this inv also refreshes h-ring lines cached >= chunkT steps ago)
      if (tid == 0) {
        while (AT_LD(gemm_done, __ATOMIC_RELAXED) < (unsigned)(ch + 1))
          __builtin_amdgcn_s_sleep(4);
        (void)AT_LD(gemm_done, __ATOMIC_ACQUIRE);    // buffer_inv: see fresh zx
        asm volatile("" ::: "memory");
      }
      __syncthreads();

      // prefetch zx for tl=0
      const unsigned short* zr0 = zxbase + (size_t)my_b * 4096 + zc;
      unsigned vi = *(const unsigned*)(zr0);
      unsigned vf = *(const unsigned*)(zr0 + 1024);
      unsigned vg = *(const unsigned*)(zr0 + 2048);
      unsigned vo = *(const unsigned*)(zr0 + 3072);

      for (int tl = 0; tl < chunkT; ++tl) {
        const int t = t0 + tl;

        // ---- z_h = h_prev @ W_hh_slice^T; h read in MFMA-fragment order ----
        // (32 independent, perfectly-coalesced 16B/lane loads -> one LLC round trip)
        const unsigned short* hp =
            hr + (size_t)(t & 15) * HSLOT + (size_t)wave * 16384 + (size_t)lane * 8;
        f32x4 r0 = fz, r1 = fz;
        bf16x8 af[32];
#pragma unroll
        for (int j = 0; j < 32; ++j) af[j] = *(const bf16x8*)(hp + (size_t)j * 512);
#pragma unroll
        for (int j = 0; j < 32; ++j) {
          int ks = j * 32;
          bf16x8 b0 = *(const bf16x8*)&smem.sW[l15][ks + (lg << 3)];
          bf16x8 b1 = *(const bf16x8*)&smem.sW[16 + l15][ks + (lg << 3)];
          r0 = MFMA16(af[j], b0, r0);
          r1 = MFMA16(af[j], b1, r1);
        }
        __syncthreads();
#pragma unroll
        for (int r = 0; r < 4; ++r) {
          smem.u.rec.z[wave * 16 + (lg << 2) + r][l15] = r0[r];
          smem.u.rec.z[wave * 16 + (lg << 2) + r][16 + l15] = r1[r];
        }
        __syncthreads();

        int hc = 2 * q;
        float zi0 = smem.u.rec.z[my_b][hc]          + biasv[0][0] + bf2f(vi & 0xffffu);
        float zi1 = smem.u.rec.z[my_b][hc + 1]      + biasv[0][1] + bf2f(vi >> 16);
        float zf0 = smem.u.rec.z[my_b][8 + hc]      + biasv[1][0] + bf2f(vf & 0xffffu);
        float zf1 = smem.u.rec.z[my_b][8 + hc + 1]  + biasv[1][1] + bf2f(vf >> 16);
        float zg0 = smem.u.rec.z[my_b][16 + hc]     + biasv[2][0] + bf2f(vg & 0xffffu);
        float zg1 = smem.u.rec.z[my_b][16 + hc + 1] + biasv[2][1] + bf2f(vg >> 16);
        float zo0 = smem.u.rec.z[my_b][24 + hc]     + biasv[3][0] + bf2f(vo & 0xffffu);
        float zo1 = smem.u.rec.z[my_b][24 + hc + 1] + biasv[3][1] + bf2f(vo >> 16);

        cc0 = sigf(zf0) * cc0 + sigf(zi0) * tanh_(zg0);
        cc1 = sigf(zf1) * cc1 + sigf(zi1) * tanh_(zg1);
        float h0 = sigf(zo0) * tanh_(cc0);
        float h1 = sigf(zo1) * tanh_(cc1);

        if (t == my_tsel) {
          finalb[(size_t)my_b * 1024 + zc]     = my_pad ? 0.f : h0;
          finalb[(size_t)my_b * 1024 + zc + 1] = my_pad ? 0.f : h1;
        }
        // store h_{t+1} into ring slot (t+1)&15 in fragment order (sc1 -> LLC)
        unsigned hp32 = (unsigned)f2bf(h0) | ((unsigned)f2bf(h1) << 16);
        AT_ST((unsigned*)(hr + (size_t)((t + 1) & 15) * HSLOT + hwe), hp32,
              __ATOMIC_RELAXED);

        // prefetch next step's zx before the barrier (slot data stable in-chunk)
        if (tl + 1 < chunkT) {
          const unsigned short* zn = zxbase + (size_t)((tl + 1) * 64 + my_b) * 4096 + zc;
          vi = *(const unsigned*)(zn);
          vf = *(const unsigned*)(zn + 1024);
          vg = *(const unsigned*)(zn + 2048);
          vo = *(const unsigned*)(zn + 3072);
        }
        gbar_rec(bar, wg, ++bt);
      }
      if (wg == 0 && tid == 0) AT_ST(rec_done, (unsigned)(ch + 1), __ATOMIC_RELAXED);
    }
  } else {
    // ================= GEMM ROLE (zx producer, one chunk ahead) =================
    const int gw = wg - 128;
    unsigned gt = 0;
    for (int ch = 0; ch < nChunks; ++ch) {
      // slot ch&1 was last consumed in chunk ch-2; wait until rec finished it
      if (tid == 0 && ch >= 2) {
        while (AT_LD(rec_done, __ATOMIC_RELAXED) < (unsigned)(ch - 1))
          __builtin_amdgcn_s_sleep(4);
        asm volatile("" ::: "memory");
      }
      __syncthreads();

      const int t0 = ch * chunkT;
      unsigned short* zx = zxr + (size_t)(ch & 1) * slotE;
      const int pmN = chunkT >> 1;
      const int npatch = pmN * 16;

      for (int p = gw; p < npatch; p += 128) {
        const int pm = p % pmN;
        const int n0 = (p / pmN) * 256;
        f32x4 acc[8][4];
#pragma unroll
        for (int mt = 0; mt < 8; ++mt)
#pragma unroll
          for (int nt = 0; nt < 4; ++nt) acc[mt][nt] = fz;

        for (int kc = 0; kc < 512; kc += 64) {
          __syncthreads();
          {  // stage A: gathered embedding rows ([128 m][64 k])
            int r = tid >> 1, half = (tid & 1) << 5;
            int tl = pm * 2 + (r >> 6), b = r & 63;
            int erow = x[b * 512 + t0 + tl];
            if (wembb) {                       // bf16 gather: pure uint4 copies
              const unsigned short* srcp = wembb + (size_t)erow * 512 + kc + half;
#pragma unroll
              for (int j = 0; j < 32; j += 8)
                *(uint4*)&smem.u.g.A[r][half + j] = *(const uint4*)(srcp + j);
            } else {                           // fp32 gather + convert
              const float* srcp = Wemb + (size_t)erow * 512 + kc + half;
#pragma unroll
              for (int j = 0; j < 32; j += 4) {
                float4 v = *(const float4*)(srcp + j);
                uint2 pk;
                pk.x = (unsigned)f2bf(v.x) | ((unsigned)f2bf(v.y) << 16);
                pk.y = (unsigned)f2bf(v.z) | ((unsigned)f2bf(v.w) << 16);
                *(uint2*)&smem.u.g.A[r][half + j] = pk;
              }
            }
          }
          {  // stage B: W_ih rows [n0 .. n0+255]  ([256 n][64 k])
            const unsigned short* srcp = Wihb + (size_t)(n0 + tid) * 512 + kc;
#pragma unroll
            for (int j = 0; j < 64; j += 8)
              *(uint4*)&smem.u.g.Bt[tid][j] = *(const uint4*)(srcp + j);
          }
          __syncthreads();
#pragma unroll
          for (int ks = 0; ks < 64; ks += 32) {
            bf16x8 af[8];
#pragma unroll
            for (int mt = 0; mt < 8; ++mt)
              af[mt] = *(const bf16x8*)&smem.u.g.A[mt * 16 + l15][ks + (lg << 3)];
#pragma unroll
            for (int nt = 0; nt < 4; ++nt) {
              bf16x8 bfr =
                  *(const bf16x8*)&smem.u.g.Bt[(wave * 4 + nt) * 16 + l15][ks + (lg << 3)];
#pragma unroll
              for (int mt = 0; mt < 8; ++mt)
                acc[mt][nt] = MFMA16(af[mt], bfr, acc[mt][nt]);
            }
          }
        }
        // store acc -> zx slot through LDS (coalesced), two 128-col halves
#pragma unroll
        for (int h = 0; h < 2; ++h) {
          __syncthreads();
          if ((wave >> 1) == h) {
#pragma unroll
            for (int mt = 0; mt < 8; ++mt)
#pragma unroll
              for (int nt = 0; nt < 4; ++nt)
#pragma unroll
                for (int r = 0; r < 4; ++r)
                  smem.u.zst.zs[mt * 16 + (lg << 2) + r][(wave & 1) * 64 + nt * 16 + l15] =
                      f2bf(acc[mt][nt][r]);
          }
          __syncthreads();
          int m = tid >> 1, qq = (tid & 1) << 6;
          int tl2 = pm * 2 + (m >> 6), bb = m & 63;
          unsigned short* dst = zx + ((size_t)(tl2 * 64 + bb)) * 4096 + n0 + h * 128 + qq;
#pragma unroll
          for (int j = 0; j < 64; j += 8)
            *(uint4*)(dst + j) = *(const uint4*)&smem.u.zst.zs[m][qq + j];
        }
      }
      gbar_gemm(bar, ++gt);                          // release: flush zx to LLC
      if (wg == 128 && tid == 0) AT_ST(gemm_done, gt, __ATOMIC_RELAXED);
    }
  }
}

extern "C" void kernel_launch(void* const* d_in, const int* in_sizes, int n_in,
                              void* d_out, int out_size, void* d_ws, size_t ws_size,
                              hipStream_t stream) {
  (void)in_sizes; (void)n_in; (void)out_size;
  const int*   x    = (const int*)  d_in[0];
  const float* Wemb = (const float*)d_in[1];
  const float* Wih  = (const float*)d_in[2];
  const float* Whh  = (const float*)d_in[3];
  const float* bih  = (const float*)d_in[4];
  const float* bhh  = (const float*)d_in[5];
  const float* Wout = (const float*)d_in[6];
  const float* bout = (const float*)d_in[7];
  float* out = (float*)d_out;
  char* ws = (char*)d_ws;

  constexpr size_t OFF_WIH = 0;
  constexpr size_t OFF_WHH = OFF_WIH + (size_t)4096 * 512 * 2;    //  4 MB
  constexpr size_t OFF_HR  = OFF_WHH + (size_t)4096 * 1024 * 2;   // +8 MB
  constexpr size_t OFF_FIN = OFF_HR + (size_t)16 * HSLOT * 2;     // +2.06 MB
  constexpr size_t OFF_TS  = OFF_FIN + (size_t)64 * 1024 * 4;     // +256 KB
  constexpr size_t OFF_PS  = OFF_TS + 4096;
  constexpr size_t OFF_BAR = OFF_PS + 4096;
  constexpr size_t OFF_WEB = OFF_BAR + 4096;
  constexpr size_t WEB_SZ  = (size_t)32000 * 512 * 2;             // 32 MB

  // adaptive: prefer bf16-Wemb + chunkT=16; degrade gracefully
  int chunkT = 16;
  bool wbf = true;
  auto need = [&](int ct, bool wb) -> size_t {
    return OFF_WEB + (wb ? WEB_SZ : 0) + (size_t)2 * ct * 64 * 4096 * 2;
  };
  if (need(chunkT, wbf) > ws_size) {
    if (need(8, true) <= ws_size) chunkT = 8;
    else if (need(16, false) <= ws_size) wbf = false;
    else {
      wbf = false;
      while (chunkT > 2 && need(chunkT, false) > ws_size) chunkT >>= 1;
    }
  }
  const size_t OFF_ZX = OFF_WEB + (wbf ? WEB_SZ : 0);

  unsigned short* wihb  = (unsigned short*)(ws + OFF_WIH);
  unsigned short* whhb  = (unsigned short*)(ws + OFF_WHH);
  unsigned short* hr    = (unsigned short*)(ws + OFF_HR);
  float* finalb         = (float*)(ws + OFF_FIN);
  int* tsel             = (int*)(ws + OFF_TS);
  int* padsel           = (int*)(ws + OFF_PS);
  unsigned* bar         = (unsigned*)(ws + OFF_BAR);
  unsigned short* wembb = wbf ? (unsigned short*)(ws + OFF_WEB) : (unsigned short*)nullptr;
  unsigned short* zxr   = (unsigned short*)(ws + OFF_ZX);

  hipMemsetAsync(ws + OFF_BAR, 0, 4096, stream);    // barrier/handshake state = 0
  k_conv<<<2048, 256, 0, stream>>>(Wih, Whh, Wemb, wihb, whhb, wembb);
  k_tsel<<<1, 512, 0, stream>>>(x, tsel, padsel);
  k_main<<<256, 256, 0, stream>>>(x, Wemb, bih, bhh, wihb, whhb, wembb, hr, finalb,
                                  tsel, padsel, zxr, bar, chunkT);
  k_logits<<<1, 256, 0, stream>>>(finalb, Wout, bout, out);
}